// Round 15
// baseline (256.262 us; speedup 1.0000x reference)
//
#include <hip/hip_runtime.h>

#define NT 256   // 4 independent waves per block; no barriers anywhere

typedef float v2f __attribute__((ext_vector_type(2)));
typedef float f4u __attribute__((ext_vector_type(4), aligned(4)));

// Gaussian(sigma=1.5, 11 taps), normalized; 0 outside [0,10]
__device__ __forceinline__ constexpr float Wj(int j) {
    return (j < 0 || j > 10) ? 0.f :
           (j == 0 || j == 10) ? 0.00102838f :
           (j == 1 || j == 9)  ? 0.00759878f :
           (j == 2 || j == 8)  ? 0.03600077f :
           (j == 3 || j == 7)  ? 0.10936069f :
           (j == 4 || j == 6)  ? 0.21300553f : 0.26601172f;
}

// Sliding-window MS-SSIM level kernel, depth-2 pipeline, slim body.
// Round-15: chunkRows halved at every level (pure-TLP round): grid supplies
// the waves the latency model needs (VGPR 80 -> 6 waves/SIMD possible).
template<bool EDGE>
__global__ __attribute__((amdgpu_flat_work_group_size(NT, NT), amdgpu_waves_per_eu(2, 4)))
void msssim_slide(
    const float* __restrict__ x1, const float* __restrict__ x2, int strideIn,
    float* __restrict__ p1, float* __restrict__ p2, int strideOut,
    float* __restrict__ accCS, float* __restrict__ accSSIM,
    int H, int W, int stripBase, int stripStep, int nStrips,
    int chunksY, int chunkRows)
{
    const int t = threadIdx.x;
    const int lane = t & 63;

    // ---- bijective XCD swizzle (gridDim.x always a multiple of 8) ----
    const int cpx = gridDim.x >> 3;
    const int lb = (blockIdx.x & 7) * cpx + (blockIdx.x >> 3);
    const int wid = lb * (NT / 64) + (t >> 6);

    const int perImg = nStrips * chunksY;
    const int img = wid / perImg;
    const int rem = wid - img * perImg;
    const int sidx = rem / chunksY;            // vertical-first within image
    const int chunk = rem - sidx * chunksY;
    const int strip = stripBase + sidx * stripStep;
    const int cc = strip * 64 + lane;          // my output column
    const int r0 = chunk * chunkRows;          // first output row (EVEN)
    const int hEnd = r0 + chunkRows + 5;       // last input row + 1
    const bool laneValid = (cc < W);
    const bool doPool = (p1 != nullptr);

    const size_t imgIn = (size_t)img * H * strideIn;
    const float* __restrict__ base1 = x1 + imgIn;
    const float* __restrict__ base2 = x2 + imgIn;
    const size_t imgOut = doPool ? (size_t)img * (H >> 1) * strideOut : 0;
    float* __restrict__ q1 = doPool ? (p1 + imgOut) : nullptr;
    float* __restrict__ q2 = doPool ? (p2 + imgOut) : nullptr;

    float nA1[12], nA2[12], nB1[12], nB2[12];  // ping-pong row windows
    v2f psd[11], psq[11];       // pending V-outputs ring (assign-first lifecycle)
    float prs1 = 0.f, prs2 = 0.f;  // pool row-pair partial sums
    float cs_s = 0.f, ssim_s = 0.f;

    auto loadRow = [&](int h, float (&d1)[12], float (&d2)[12]) {
        if (h < 0 || h >= H || !laneValid) return;   // zero-pad rows / idle lanes
        const float* __restrict__ r1 = base1 + (size_t)h * strideIn;
        const float* __restrict__ r2 = base2 + (size_t)h * strideIn;
        if constexpr (!EDGE) {
            const f4u* a4 = reinterpret_cast<const f4u*>(r1 + (cc - 5));
            const f4u* b4 = reinterpret_cast<const f4u*>(r2 + (cc - 5));
            f4u A0 = a4[0], A1 = a4[1], A2 = a4[2];
            f4u B0 = b4[0], B1 = b4[1], B2 = b4[2];
#pragma unroll
            for (int j = 0; j < 4; ++j) { d1[j] = A0[j]; d1[4 + j] = A1[j]; d1[8 + j] = A2[j]; }
#pragma unroll
            for (int j = 0; j < 4; ++j) { d2[j] = B0[j]; d2[4 + j] = B1[j]; d2[8 + j] = B2[j]; }
        } else {
            // clamped + masked scalar path (level-0 image column borders)
#pragma unroll
            for (int j = 0; j < 12; ++j) {
                int col = cc + j - 5;
                int cl = col < 0 ? 0 : (col > W - 1 ? W - 1 : col);
                float a = r1[cl], b = r2[cl];
                bool ok = (col >= 0) && (col < W);
                d1[j] = ok ? a : 0.f;
                d2[j] = ok ? b : 0.f;
            }
        }
    };

    // prologue: rows r0-5 (buffer A) and r0-4 (buffer B) in flight
    loadRow(r0 - 5, nA1, nA2);
    loadRow(r0 - 4, nB1, nB2);

    const float C1 = 0.0001f, C2 = 0.0009f;

    // hb = r0-5 is ODD (r0 even) => pp even <-> h odd, pp odd <-> h even
    for (int hb = r0 - 5; hb < hEnd; hb += 22) {
#pragma unroll
        for (int pp = 0; pp < 22; ++pp) {
            const int h = hb + pp;
            if (h < hEnd) {
                const int p = pp % 11;                       // ring phase
                float (&x1w)[12] = (pp & 1) ? nB1 : nA1;     // compile-time parity
                float (&x2w)[12] = (pp & 1) ? nB2 : nA2;

                // ---- 1. consume buffered row h: H-filter 4 moments ----
                v2f acc_sd = (v2f){0.f, 0.f}, acc_sq = (v2f){0.f, 0.f};
                if (h >= 0 && h < H) {
                    if (doPool && h >= r0 && h < r0 + chunkRows) {
                        if ((pp & 1) == 1) {                 // h EVEN: save pair
                            prs1 = x1w[5] + x1w[6];
                            prs2 = x2w[5] + x2w[6];
                        } else if (!(lane & 1) && laneValid) {  // h ODD: write pooled
                            size_t po = (size_t)(h >> 1) * strideOut + (cc >> 1);
                            q1[po] = 0.25f * (prs1 + x1w[5] + x1w[6]);
                            q2[po] = 0.25f * (prs2 + x2w[5] + x2w[6]);
                        }
                    }
#pragma unroll
                    for (int j = 0; j < 11; ++j) {
                        // {s, d} = {x1+x2, x1-x2} in ONE packed fma
                        v2f xx1 = {x1w[j], x1w[j]};
                        v2f xx2 = {x2w[j], x2w[j]};
                        v2f sd = __builtin_elementwise_fma((v2f){1.f, -1.f}, xx2, xx1);
                        v2f w2 = {Wj(j), Wj(j)};
                        acc_sd = __builtin_elementwise_fma(w2, sd, acc_sd);
                        acc_sq = __builtin_elementwise_fma(w2, sd * sd, acc_sq);
                    }
                }
                // ---- 2. issue row h+2 into the just-consumed buffer ----
                if (h + 2 < hEnd) loadRow(h + 2, x1w, x2w);
                // ---- 3. V-ring update: row h feeds outputs h-5 .. h+5 ----
#pragma unroll
                for (int k = 0; k < 11; ++k) {
                    const int slot = (p + 5 - k + 11) % 11;
                    v2f w2 = {Wj(k), Wj(k)};
                    if (k == 0) {
                        psd[slot] = w2 * acc_sd;
                        psq[slot] = w2 * acc_sq;
                    } else {
                        psd[slot] = __builtin_elementwise_fma(w2, acc_sd, psd[slot]);
                        psq[slot] = __builtin_elementwise_fma(w2, acc_sq, psq[slot]);
                    }
                }
                // ---- 4. emit completed output row o = h-5 (rcp-based) ----
                if (h - 5 >= r0) {
                    const int es = (p + 6) % 11;
                    v2f m2 = psd[es] * psd[es];      // {Sm^2, Dm^2}
                    v2f t1 = psq[es] - m2;           // {SSm-Sm^2, DDm-Dm^2}
                    float num_cs = 0.5f * (t1.x - t1.y) + C2;   // 2*sigma12 + C2
                    float den_cs = 0.5f * (t1.x + t1.y) + C2;   // sig1+sig2 + C2
                    float num_ss = 0.5f * (m2.x - m2.y) + C1;   // 2*mu12 + C1
                    float den_ss = 0.5f * (m2.x + m2.y) + C1;   // mu1^2+mu2^2 + C1
                    float cs = num_cs * __builtin_amdgcn_rcpf(den_cs);
                    float ss = num_ss * cs * __builtin_amdgcn_rcpf(den_ss);
                    if (laneValid) { cs_s += cs; ssim_s += ss; }
                }
            }
        }
    }

    // ---- wave reduction -> 2 atomics per wave ----
#pragma unroll
    for (int off = 32; off > 0; off >>= 1) {
        cs_s += __shfl_down(cs_s, off);
        ssim_s += __shfl_down(ssim_s, off);
    }
    if (lane == 0) {
        atomicAdd(&accCS[img], cs_s);
        atomicAdd(&accSSIM[img], ssim_s);
    }
}

// Zero the 8-col left/right halos of the padded level-1..4 arrays (~2 MB)
// One thread per padded row (both arrays); two f4u stores per side.
__global__ void halo_zero_kernel(float* __restrict__ w1_1, float* __restrict__ w2_1,
                                 float* __restrict__ w1_2, float* __restrict__ w2_2,
                                 float* __restrict__ w1_3, float* __restrict__ w2_3,
                                 float* __restrict__ w1_4, float* __restrict__ w2_4) {
    int idx = blockIdx.x * blockDim.x + threadIdx.x;   // [0, 2*23040)
    int which = idx >= 23040;
    int r = which ? idx - 23040 : idx;
    float* base;
    int stride, Wl;
    if (r < 12288)      { base = which ? w2_1 : w1_1; stride = 272; Wl = 256; }
    else if (r < 18432) { base = which ? w2_2 : w1_2; stride = 144; Wl = 128; r -= 12288; }
    else if (r < 21504) { base = which ? w2_3 : w1_3; stride = 80;  Wl = 64;  r -= 18432; }
    else                { base = which ? w2_4 : w1_4; stride = 48;  Wl = 32;  r -= 21504; }
    float* row = base + (size_t)r * stride;
    f4u z = {0.f, 0.f, 0.f, 0.f};
    *(f4u*)(row - 8) = z;
    *(f4u*)(row - 4) = z;
    *(f4u*)(row + Wl) = z;
    *(f4u*)(row + Wl + 4) = z;
}

// acc layout: CS sums at acc[l*48 + img]; SSIM sums at acc[256 + l*48 + img]
__global__ void finalize_kernel(const float* __restrict__ acc, float* __restrict__ out) {
    __shared__ float vals[16];
    int t = threadIdx.x;
    if (t < 16) {
        const float w[5] = {0.0448f, 0.2856f, 0.3001f, 0.2363f, 0.1333f};
        float v = 1.f;
#pragma unroll
        for (int l = 0; l < 5; ++l) {
            int Hl = 512 >> l;
            float denom = 3.f * (float)Hl * (float)Hl;
            const float* src = (l < 4) ? (acc + l * 48) : (acc + 256 + l * 48);
            float m = src[3 * t] + src[3 * t + 1] + src[3 * t + 2];
            m = m / denom;
            m = fmaxf(m, 0.f);
            v *= powf(m, w[l]);
        }
        vals[t] = v;
    }
    __syncthreads();
    if (t == 0) {
        float s = 0.f;
        for (int i = 0; i < 16; ++i) s += vals[i];
        out[0] = s / 16.f;
    }
}

extern "C" void kernel_launch(void* const* d_in, const int* in_sizes, int n_in,
                              void* d_out, int out_size, void* d_ws, size_t ws_size,
                              hipStream_t stream) {
    const float* img1 = (const float*)d_in[0];
    const float* img2 = (const float*)d_in[1];
    float* out = (float*)d_out;
    float* ws = (float*)d_ws;

    float* acc = ws;
    size_t off = 512;

    // level arrays: padded stride Wl+16, pointer offset +8 (column halo)
    float* a1[5];
    float* a2[5];
    int strideL[5];
    a1[0] = (float*)img1; a2[0] = (float*)img2; strideL[0] = 512;
    for (int l = 1; l < 5; ++l) {
        int Hl = 512 >> l;
        strideL[l] = Hl + 16;
        a1[l] = ws + off + 8; off += (size_t)48 * Hl * strideL[l];
    }
    for (int l = 1; l < 5; ++l) {
        int Hl = 512 >> l;
        a2[l] = ws + off + 8; off += (size_t)48 * Hl * strideL[l];
    }

    hipMemsetAsync(acc, 0, 512 * sizeof(float), stream);
    halo_zero_kernel<<<(2 * 23040 + 255) / 256, 256, 0, stream>>>(
        a1[1], a2[1], a1[2], a2[2], a1[3], a2[3], a1[4], a2[4]);

    // ---- level 0: interior strips (vector path) + edge strips (clamp path) ----
    {
        int chunksY = 512 / 16;   // chunkRows 16
        int wavesI = 48 * 6 * chunksY;      // 9216 -> 2304 blocks
        msssim_slide<false><<<wavesI / 4, NT, 0, stream>>>(
            a1[0], a2[0], 512, a1[1], a2[1], strideL[1],
            acc, acc + 256, 512, 512, /*stripBase*/1, /*step*/1, /*n*/6,
            chunksY, 16);
        int wavesE = 48 * 2 * chunksY;      // 3072 -> 768 blocks
        msssim_slide<true><<<wavesE / 4, NT, 0, stream>>>(
            a1[0], a2[0], 512, a1[1], a2[1], strideL[1],
            acc, acc + 256, 512, 512, /*stripBase*/0, /*step*/7, /*n*/2,
            chunksY, 16);
    }
    // ---- levels 1..4 (padded -> pure vector path) ----
    for (int l = 1; l < 5; ++l) {
        int Hl = 512 >> l;
        int strips = (Hl + 63) / 64;                    // 4,2,1,1
        int chunkRows = (l <= 2) ? 8 : 4;
        int chunksY = Hl / chunkRows;
        int waves = 48 * strips * chunksY;
        float* pp1 = (l < 4) ? a1[l + 1] : nullptr;
        float* pp2 = (l < 4) ? a2[l + 1] : nullptr;
        int so = (l < 4) ? strideL[l + 1] : 0;
        msssim_slide<false><<<waves / 4, NT, 0, stream>>>(
            a1[l], a2[l], strideL[l], pp1, pp2, so,
            acc + l * 48, acc + 256 + l * 48,
            Hl, Hl, 0, 1, strips, chunksY, chunkRows);
    }
    finalize_kernel<<<1, 64, 0, stream>>>(acc, out);
}

// Round 16
// 248.918 us; speedup vs baseline: 1.0295x; 1.0295x over previous
//
#include <hip/hip_runtime.h>

#define NT 256   // 4 independent waves per block; no barriers anywhere

typedef float v2f __attribute__((ext_vector_type(2)));
typedef float f4u __attribute__((ext_vector_type(4), aligned(4)));
typedef float f2u __attribute__((ext_vector_type(2), aligned(4)));

// Gaussian(sigma=1.5, 11 taps), normalized; 0 outside [0,10]
__device__ __forceinline__ constexpr float Wj(int j) {
    return (j < 0 || j > 10) ? 0.f :
           (j == 0 || j == 10) ? 0.00102838f :
           (j == 1 || j == 9)  ? 0.00759878f :
           (j == 2 || j == 8)  ? 0.03600077f :
           (j == 3 || j == 7)  ? 0.10936069f :
           (j == 4 || j == 6)  ? 0.21300553f : 0.26601172f;
}

// Sliding-window MS-SSIM, 2 COLUMNS PER LANE (128-col strips).
// Loads: 4 x f4 per image per row at 8B lane stride -> ~9 lines/instr,
// 8 instr/row (vs 12 instr x 17 lines before) - attacks the L1 lookup wall.
// Ring: separate {S,D}/{SS,DD} v2f rings per owned column (88 VGPR).
template<bool EDGE>
__global__ __attribute__((amdgpu_flat_work_group_size(NT, NT), amdgpu_waves_per_eu(2, 4)))
void msssim_slide(
    const float* __restrict__ x1, const float* __restrict__ x2, int strideIn,
    float* __restrict__ p1, float* __restrict__ p2, int strideOut,
    float* __restrict__ accCS, float* __restrict__ accSSIM,
    int H, int W, int stripBase, int stripStep, int nStrips,
    int chunksY, int chunkRows)
{
    const int t = threadIdx.x;
    const int lane = t & 63;

    // ---- bijective XCD swizzle (gridDim.x always a multiple of 8) ----
    const int cpx = gridDim.x >> 3;
    const int lb = (blockIdx.x & 7) * cpx + (blockIdx.x >> 3);
    const int wid = lb * (NT / 64) + (t >> 6);

    const int perImg = nStrips * chunksY;
    const int img = wid / perImg;
    const int rem = wid - img * perImg;
    const int sidx = rem / chunksY;            // vertical-first within image
    const int chunk = rem - sidx * chunksY;
    const int strip = stripBase + sidx * stripStep;
    const int c0 = strip * 128 + 2 * lane;     // my two columns: c0, c0+1
    const int r0 = chunk * chunkRows;          // first output row (EVEN)
    const int hEnd = r0 + chunkRows + 5;       // last input row + 1
    const bool laneValid = (c0 < W);
    const bool doPool = (p1 != nullptr);

    const size_t imgIn = (size_t)img * H * strideIn;
    const float* __restrict__ base1 = x1 + imgIn;
    const float* __restrict__ base2 = x2 + imgIn;
    const size_t imgOut = doPool ? (size_t)img * (H >> 1) * strideOut : 0;
    float* __restrict__ q1 = doPool ? (p1 + imgOut) : nullptr;
    float* __restrict__ q2 = doPool ? (p2 + imgOut) : nullptr;

    float W1[16], W2[16];          // row window: float index c0-8+m
    v2f rsd0[11], rsq0[11];        // col c0   pending ring {S,D}/{SS,DD}
    v2f rsd1[11], rsq1[11];        // col c0+1
    float prs1 = 0.f, prs2 = 0.f;  // pool row-pair partial sums
    float cs_s = 0.f, ssim_s = 0.f;

    auto loadRow = [&](int h) {
        if (h < 0 || h >= H || !laneValid) return;   // zero-pad rows / idle lanes
        const float* __restrict__ r1 = base1 + (size_t)h * strideIn;
        const float* __restrict__ r2 = base2 + (size_t)h * strideIn;
        if constexpr (!EDGE) {
            const f4u* a4 = reinterpret_cast<const f4u*>(r1 + (c0 - 8));
            const f4u* b4 = reinterpret_cast<const f4u*>(r2 + (c0 - 8));
            f4u A0 = a4[0], A1 = a4[1], A2 = a4[2], A3 = a4[3];
            f4u B0 = b4[0], B1 = b4[1], B2 = b4[2], B3 = b4[3];
#pragma unroll
            for (int j = 0; j < 4; ++j) {
                W1[j] = A0[j]; W1[4 + j] = A1[j]; W1[8 + j] = A2[j]; W1[12 + j] = A3[j];
                W2[j] = B0[j]; W2[4 + j] = B1[j]; W2[8 + j] = B2[j]; W2[12 + j] = B3[j];
            }
        } else {
            // clamped + masked float2 path (L0 border strips); fills W[2..15]
#pragma unroll
            for (int m = 0; m < 7; ++m) {
                int i2 = c0 - 6 + 2 * m;                 // even
                int cl = i2 < 0 ? 0 : (i2 > W - 2 ? W - 2 : i2);
                bool ok = (i2 >= 0) & (i2 < W);
                f2u va = *(const f2u*)(r1 + cl);
                f2u vb = *(const f2u*)(r2 + cl);
                W1[2 + 2 * m] = ok ? va.x : 0.f;
                W1[3 + 2 * m] = ok ? va.y : 0.f;
                W2[2 + 2 * m] = ok ? vb.x : 0.f;
                W2[3 + 2 * m] = ok ? vb.y : 0.f;
            }
        }
    };

    loadRow(r0 - 5);   // prologue

    const float C1 = 0.0001f, C2 = 0.0009f;

    for (int hb = r0 - 5; hb < hEnd; hb += 11) {
#pragma unroll
        for (int p = 0; p < 11; ++p) {
            const int h = hb + p;
            if (h < hEnd) {
                // ---- 1. consume window row h: H-filter both columns ----
                v2f asd0 = (v2f){0.f, 0.f}, asq0 = (v2f){0.f, 0.f};
                v2f asd1 = (v2f){0.f, 0.f}, asq1 = (v2f){0.f, 0.f};
                if (h >= 0 && h < H) {
                    if (doPool && h >= r0 && h < r0 + chunkRows) {
                        float ra = W1[8] + W1[9];   // cols c0, c0+1
                        float rb = W2[8] + W2[9];
                        if ((h & 1) == 0) { prs1 = ra; prs2 = rb; }
                        else if (laneValid) {       // dense store: 1 float/lane
                            size_t po = (size_t)(h >> 1) * strideOut + (c0 >> 1);
                            q1[po] = 0.25f * (prs1 + ra);
                            q2[po] = 0.25f * (prs2 + rb);
                        }
                    }
#pragma unroll
                    for (int m = 3; m <= 14; ++m) {
                        v2f xa = {W1[m], W1[m]};
                        v2f xb = {W2[m], W2[m]};
                        v2f sd = __builtin_elementwise_fma((v2f){1.f, -1.f}, xb, xa);
                        v2f sq = sd * sd;
                        constexpr float dummy = 0.f; (void)dummy;
                        const float w0 = Wj(m - 3);     // tap for col c0
                        const float w1 = Wj(m - 4);     // tap for col c0+1
                        if (w0 != 0.f) {
                            asd0 = __builtin_elementwise_fma((v2f){w0, w0}, sd, asd0);
                            asq0 = __builtin_elementwise_fma((v2f){w0, w0}, sq, asq0);
                        }
                        if (w1 != 0.f) {
                            asd1 = __builtin_elementwise_fma((v2f){w1, w1}, sd, asd1);
                            asq1 = __builtin_elementwise_fma((v2f){w1, w1}, sq, asq1);
                        }
                    }
                }
                // ---- 2. issue row h+1 into the (consumed) window ----
                if (h + 1 < hEnd) loadRow(h + 1);
                // ---- 3. V-ring update: row h feeds outputs h-5 .. h+5 ----
#pragma unroll
                for (int k = 0; k < 11; ++k) {
                    const int slot = (p + 5 - k + 11) % 11;
                    const float w = Wj(k);
                    v2f wv = {w, w};
                    if (k == 0) {
                        rsd0[slot] = wv * asd0; rsq0[slot] = wv * asq0;
                        rsd1[slot] = wv * asd1; rsq1[slot] = wv * asq1;
                    } else {
                        rsd0[slot] = __builtin_elementwise_fma(wv, asd0, rsd0[slot]);
                        rsq0[slot] = __builtin_elementwise_fma(wv, asq0, rsq0[slot]);
                        rsd1[slot] = __builtin_elementwise_fma(wv, asd1, rsd1[slot]);
                        rsq1[slot] = __builtin_elementwise_fma(wv, asq1, rsq1[slot]);
                    }
                }
                // ---- 4. emit completed output row o = h-5, both columns ----
                if (h - 5 >= r0) {
                    const int es = (p + 6) % 11;
                    v2f m20 = rsd0[es] * rsd0[es];
                    v2f t10 = rsq0[es] - m20;
                    float ncs0 = 0.5f * (t10.x - t10.y) + C2;
                    float dcs0 = 0.5f * (t10.x + t10.y) + C2;
                    float nss0 = 0.5f * (m20.x - m20.y) + C1;
                    float dss0 = 0.5f * (m20.x + m20.y) + C1;
                    float cs0 = ncs0 * __builtin_amdgcn_rcpf(dcs0);
                    float ss0 = nss0 * cs0 * __builtin_amdgcn_rcpf(dss0);
                    v2f m21 = rsd1[es] * rsd1[es];
                    v2f t11 = rsq1[es] - m21;
                    float ncs1 = 0.5f * (t11.x - t11.y) + C2;
                    float dcs1 = 0.5f * (t11.x + t11.y) + C2;
                    float nss1 = 0.5f * (m21.x - m21.y) + C1;
                    float dss1 = 0.5f * (m21.x + m21.y) + C1;
                    float cs1 = ncs1 * __builtin_amdgcn_rcpf(dcs1);
                    float ss1 = nss1 * cs1 * __builtin_amdgcn_rcpf(dss1);
                    if (laneValid) { cs_s += cs0 + cs1; ssim_s += ss0 + ss1; }
                }
            }
        }
    }

    // ---- wave reduction -> 2 atomics per wave ----
#pragma unroll
    for (int off = 32; off > 0; off >>= 1) {
        cs_s += __shfl_down(cs_s, off);
        ssim_s += __shfl_down(ssim_s, off);
    }
    if (lane == 0) {
        atomicAdd(&accCS[img], cs_s);
        atomicAdd(&accSSIM[img], ssim_s);
    }
}

// Zero the 8-col left/right halos of the padded level-1..4 arrays (~2 MB)
__global__ void halo_zero_kernel(float* __restrict__ w1_1, float* __restrict__ w2_1,
                                 float* __restrict__ w1_2, float* __restrict__ w2_2,
                                 float* __restrict__ w1_3, float* __restrict__ w2_3,
                                 float* __restrict__ w1_4, float* __restrict__ w2_4) {
    int idx = blockIdx.x * blockDim.x + threadIdx.x;   // [0, 2*23040)
    if (idx >= 2 * 23040) return;
    int which = idx >= 23040;
    int r = which ? idx - 23040 : idx;
    float* base;
    int stride, Wl;
    if (r < 12288)      { base = which ? w2_1 : w1_1; stride = 272; Wl = 256; }
    else if (r < 18432) { base = which ? w2_2 : w1_2; stride = 144; Wl = 128; r -= 12288; }
    else if (r < 21504) { base = which ? w2_3 : w1_3; stride = 80;  Wl = 64;  r -= 18432; }
    else                { base = which ? w2_4 : w1_4; stride = 48;  Wl = 32;  r -= 21504; }
    float* row = base + (size_t)r * stride;
    f4u z = {0.f, 0.f, 0.f, 0.f};
    *(f4u*)(row - 8) = z;
    *(f4u*)(row - 4) = z;
    *(f4u*)(row + Wl) = z;
    *(f4u*)(row + Wl + 4) = z;
}

// acc layout: CS sums at acc[l*48 + img]; SSIM sums at acc[256 + l*48 + img]
__global__ void finalize_kernel(const float* __restrict__ acc, float* __restrict__ out) {
    __shared__ float vals[16];
    int t = threadIdx.x;
    if (t < 16) {
        const float w[5] = {0.0448f, 0.2856f, 0.3001f, 0.2363f, 0.1333f};
        float v = 1.f;
#pragma unroll
        for (int l = 0; l < 5; ++l) {
            int Hl = 512 >> l;
            float denom = 3.f * (float)Hl * (float)Hl;
            const float* src = (l < 4) ? (acc + l * 48) : (acc + 256 + l * 48);
            float m = src[3 * t] + src[3 * t + 1] + src[3 * t + 2];
            m = m / denom;
            m = fmaxf(m, 0.f);
            v *= powf(m, w[l]);
        }
        vals[t] = v;
    }
    __syncthreads();
    if (t == 0) {
        float s = 0.f;
        for (int i = 0; i < 16; ++i) s += vals[i];
        out[0] = s / 16.f;
    }
}

extern "C" void kernel_launch(void* const* d_in, const int* in_sizes, int n_in,
                              void* d_out, int out_size, void* d_ws, size_t ws_size,
                              hipStream_t stream) {
    const float* img1 = (const float*)d_in[0];
    const float* img2 = (const float*)d_in[1];
    float* out = (float*)d_out;
    float* ws = (float*)d_ws;

    float* acc = ws;
    size_t off = 512;

    // level arrays: padded stride Wl+16, pointer offset +8 (column halo)
    float* a1[5];
    float* a2[5];
    int strideL[5];
    a1[0] = (float*)img1; a2[0] = (float*)img2; strideL[0] = 512;
    for (int l = 1; l < 5; ++l) {
        int Hl = 512 >> l;
        strideL[l] = Hl + 16;
        a1[l] = ws + off + 8; off += (size_t)48 * Hl * strideL[l];
    }
    for (int l = 1; l < 5; ++l) {
        int Hl = 512 >> l;
        a2[l] = ws + off + 8; off += (size_t)48 * Hl * strideL[l];
    }

    hipMemsetAsync(acc, 0, 512 * sizeof(float), stream);
    halo_zero_kernel<<<(2 * 23040 + 255) / 256, 256, 0, stream>>>(
        a1[1], a2[1], a1[2], a2[2], a1[3], a2[3], a1[4], a2[4]);

    // ---- level 0: interior strips 1,2 (cols 128..383) + edge strips 0,3 ----
    msssim_slide<false><<<768, NT, 0, stream>>>(
        a1[0], a2[0], 512, a1[1], a2[1], strideL[1],
        acc, acc + 256, 512, 512, /*base*/1, /*step*/1, /*n*/2, 32, 16);
    msssim_slide<true><<<768, NT, 0, stream>>>(
        a1[0], a2[0], 512, a1[1], a2[1], strideL[1],
        acc, acc + 256, 512, 512, /*base*/0, /*step*/3, /*n*/2, 32, 16);
    // ---- levels 1..4 (padded -> all interior) ----
    msssim_slide<false><<<384, NT, 0, stream>>>(
        a1[1], a2[1], strideL[1], a1[2], a2[2], strideL[2],
        acc + 48, acc + 256 + 48, 256, 256, 0, 1, 2, 16, 16);
    msssim_slide<false><<<192, NT, 0, stream>>>(
        a1[2], a2[2], strideL[2], a1[3], a2[3], strideL[3],
        acc + 96, acc + 256 + 96, 128, 128, 0, 1, 1, 16, 8);
    msssim_slide<false><<<96, NT, 0, stream>>>(
        a1[3], a2[3], strideL[3], a1[4], a2[4], strideL[4],
        acc + 144, acc + 256 + 144, 64, 64, 0, 1, 1, 8, 8);
    msssim_slide<false><<<96, NT, 0, stream>>>(
        a1[4], a2[4], strideL[4], nullptr, nullptr, 0,
        acc + 192, acc + 256 + 192, 32, 32, 0, 1, 1, 8, 4);

    finalize_kernel<<<1, 64, 0, stream>>>(acc, out);
}

// Round 20
// 216.216 us; speedup vs baseline: 1.1852x; 1.1512x over previous
//
#include <hip/hip_runtime.h>

#define NT 256   // 4 independent waves per block; no barriers anywhere

typedef float v2f __attribute__((ext_vector_type(2)));
typedef float f4u __attribute__((ext_vector_type(4), aligned(4)));
typedef float f4a __attribute__((ext_vector_type(4), aligned(16)));

// Gaussian(sigma=1.5, 11 taps), normalized; 0 outside [0,10]
__device__ __forceinline__ constexpr float Wj(int j) {
    return (j < 0 || j > 10) ? 0.f :
           (j == 0 || j == 10) ? 0.00102838f :
           (j == 1 || j == 9)  ? 0.00759878f :
           (j == 2 || j == 8)  ? 0.03600077f :
           (j == 3 || j == 7)  ? 0.10936069f :
           (j == 4 || j == 6)  ? 0.21300553f : 0.26601172f;
}

// Sliding-window MS-SSIM level kernel, depth-2 pipeline, slim body
// (byte-identical to the round-14 verified kernel; absmax 0.0).
template<bool EDGE>
__global__ __attribute__((amdgpu_flat_work_group_size(NT, NT), amdgpu_waves_per_eu(2, 4)))
void msssim_slide(
    const float* __restrict__ x1, const float* __restrict__ x2, int strideIn,
    float* __restrict__ p1, float* __restrict__ p2, int strideOut,
    float* __restrict__ accCS, float* __restrict__ accSSIM,
    int H, int W, int stripBase, int stripStep, int nStrips,
    int chunksY, int chunkRows)
{
    const int t = threadIdx.x;
    const int lane = t & 63;

    // ---- bijective XCD swizzle (gridDim.x always a multiple of 8) ----
    const int cpx = gridDim.x >> 3;
    const int lb = (blockIdx.x & 7) * cpx + (blockIdx.x >> 3);
    const int wid = lb * (NT / 64) + (t >> 6);

    const int perImg = nStrips * chunksY;
    const int img = wid / perImg;
    const int rem = wid - img * perImg;
    const int sidx = rem / chunksY;            // vertical-first within image
    const int chunk = rem - sidx * chunksY;
    const int strip = stripBase + sidx * stripStep;
    const int cc = strip * 64 + lane;          // my output column
    const int r0 = chunk * chunkRows;          // first output row (EVEN)
    const int hEnd = r0 + chunkRows + 5;       // last input row + 1
    const bool laneValid = (cc < W);
    const bool doPool = (p1 != nullptr);

    const size_t imgIn = (size_t)img * H * strideIn;
    const float* __restrict__ base1 = x1 + imgIn;
    const float* __restrict__ base2 = x2 + imgIn;
    const size_t imgOut = doPool ? (size_t)img * (H >> 1) * strideOut : 0;
    float* __restrict__ q1 = doPool ? (p1 + imgOut) : nullptr;
    float* __restrict__ q2 = doPool ? (p2 + imgOut) : nullptr;

    float nA1[12], nA2[12], nB1[12], nB2[12];  // ping-pong row windows
    v2f psd[11], psq[11];       // pending V-outputs ring (assign-first lifecycle)
    float prs1 = 0.f, prs2 = 0.f;  // pool row-pair partial sums
    float cs_s = 0.f, ssim_s = 0.f;

    auto loadRow = [&](int h, float (&d1)[12], float (&d2)[12]) {
        if (h < 0 || h >= H || !laneValid) return;   // zero-pad rows / idle lanes
        const float* __restrict__ r1 = base1 + (size_t)h * strideIn;
        const float* __restrict__ r2 = base2 + (size_t)h * strideIn;
        if constexpr (!EDGE) {
            const f4u* a4 = reinterpret_cast<const f4u*>(r1 + (cc - 5));
            const f4u* b4 = reinterpret_cast<const f4u*>(r2 + (cc - 5));
            f4u A0 = a4[0], A1 = a4[1], A2 = a4[2];
            f4u B0 = b4[0], B1 = b4[1], B2 = b4[2];
#pragma unroll
            for (int j = 0; j < 4; ++j) { d1[j] = A0[j]; d1[4 + j] = A1[j]; d1[8 + j] = A2[j]; }
#pragma unroll
            for (int j = 0; j < 4; ++j) { d2[j] = B0[j]; d2[4 + j] = B1[j]; d2[8 + j] = B2[j]; }
        } else {
            // clamped + masked scalar path (fallback mode only)
#pragma unroll
            for (int j = 0; j < 12; ++j) {
                int col = cc + j - 5;
                int cl = col < 0 ? 0 : (col > W - 1 ? W - 1 : col);
                float a = r1[cl], b = r2[cl];
                bool ok = (col >= 0) && (col < W);
                d1[j] = ok ? a : 0.f;
                d2[j] = ok ? b : 0.f;
            }
        }
    };

    // prologue: rows r0-5 (buffer A) and r0-4 (buffer B) in flight
    loadRow(r0 - 5, nA1, nA2);
    loadRow(r0 - 4, nB1, nB2);

    const float C1 = 0.0001f, C2 = 0.0009f;

    // hb = r0-5 is ODD (r0 even) => pp even <-> h odd, pp odd <-> h even
    for (int hb = r0 - 5; hb < hEnd; hb += 22) {
#pragma unroll
        for (int pp = 0; pp < 22; ++pp) {
            const int h = hb + pp;
            if (h < hEnd) {
                const int p = pp % 11;                       // ring phase
                float (&x1w)[12] = (pp & 1) ? nB1 : nA1;     // compile-time parity
                float (&x2w)[12] = (pp & 1) ? nB2 : nA2;

                // ---- 1. consume buffered row h: H-filter 4 moments ----
                v2f acc_sd = (v2f){0.f, 0.f}, acc_sq = (v2f){0.f, 0.f};
                if (h >= 0 && h < H) {
                    if (doPool && h >= r0 && h < r0 + chunkRows) {
                        if ((pp & 1) == 1) {                 // h EVEN: save pair
                            prs1 = x1w[5] + x1w[6];
                            prs2 = x2w[5] + x2w[6];
                        } else if (!(lane & 1) && laneValid) {  // h ODD: write pooled
                            size_t po = (size_t)(h >> 1) * strideOut + (cc >> 1);
                            q1[po] = 0.25f * (prs1 + x1w[5] + x1w[6]);
                            q2[po] = 0.25f * (prs2 + x2w[5] + x2w[6]);
                        }
                    }
#pragma unroll
                    for (int j = 0; j < 11; ++j) {
                        // {s, d} = {x1+x2, x1-x2} in ONE packed fma
                        v2f xx1 = {x1w[j], x1w[j]};
                        v2f xx2 = {x2w[j], x2w[j]};
                        v2f sd = __builtin_elementwise_fma((v2f){1.f, -1.f}, xx2, xx1);
                        v2f w2 = {Wj(j), Wj(j)};
                        acc_sd = __builtin_elementwise_fma(w2, sd, acc_sd);
                        acc_sq = __builtin_elementwise_fma(w2, sd * sd, acc_sq);
                    }
                }
                // ---- 2. issue row h+2 into the just-consumed buffer ----
                if (h + 2 < hEnd) loadRow(h + 2, x1w, x2w);
                // ---- 3. V-ring update: row h feeds outputs h-5 .. h+5 ----
#pragma unroll
                for (int k = 0; k < 11; ++k) {
                    const int slot = (p + 5 - k + 11) % 11;
                    v2f w2 = {Wj(k), Wj(k)};
                    if (k == 0) {
                        psd[slot] = w2 * acc_sd;
                        psq[slot] = w2 * acc_sq;
                    } else {
                        psd[slot] = __builtin_elementwise_fma(w2, acc_sd, psd[slot]);
                        psq[slot] = __builtin_elementwise_fma(w2, acc_sq, psq[slot]);
                    }
                }
                // ---- 4. emit completed output row o = h-5 (rcp-based) ----
                if (h - 5 >= r0) {
                    const int es = (p + 6) % 11;
                    v2f m2 = psd[es] * psd[es];      // {Sm^2, Dm^2}
                    v2f t1 = psq[es] - m2;           // {SS-Sm^2, DD-Dm^2}
                    float num_cs = 0.5f * (t1.x - t1.y) + C2;
                    float den_cs = 0.5f * (t1.x + t1.y) + C2;
                    float num_ss = 0.5f * (m2.x - m2.y) + C1;
                    float den_ss = 0.5f * (m2.x + m2.y) + C1;
                    float cs = num_cs * __builtin_amdgcn_rcpf(den_cs);
                    float ss = num_ss * cs * __builtin_amdgcn_rcpf(den_ss);
                    if (laneValid) { cs_s += cs; ssim_s += ss; }
                }
            }
        }
    }

    // ---- wave reduction -> 2 atomics per wave ----
#pragma unroll
    for (int off = 32; off > 0; off >>= 1) {
        cs_s += __shfl_down(cs_s, off);
        ssim_s += __shfl_down(ssim_s, off);
    }
    if (lane == 0) {
        atomicAdd(&accCS[img], cs_s);
        atomicAdd(&accSSIM[img], ssim_s);
    }
}

// Pad-copy both L0 inputs into stride-528 buffers with 8-col zero halos.
// One thread per 16B chunk: row = 132 f4 (2 zero | 128 data | 2 zero).
__global__ void pad_l0_kernel(const float* __restrict__ s1, const float* __restrict__ s2,
                              float* __restrict__ d1, float* __restrict__ d2) {
    const size_t PER = (size_t)48 * 512 * 132;      // f4 chunks per input
    size_t idx = (size_t)blockIdx.x * blockDim.x + threadIdx.x;
    int which = idx >= PER;
    size_t r = which ? idx - PER : idx;
    size_t row = r / 132;                            // [0, 48*512)
    int c4 = (int)(r - row * 132);                   // [0, 132)
    const float* __restrict__ src = which ? s2 : s1;
    float* __restrict__ dst = (which ? d2 : d1) + row * 528 + (size_t)c4 * 4;
    f4a v = {0.f, 0.f, 0.f, 0.f};
    if (c4 >= 2 && c4 < 130)
        v = *(const f4a*)(src + row * 512 + (size_t)(c4 - 2) * 4);
    *(f4a*)dst = v;
}

// Zero the 8-col left/right halos of the padded level-1..4 arrays
__global__ void halo_zero_kernel(float* __restrict__ w1_1, float* __restrict__ w2_1,
                                 float* __restrict__ w1_2, float* __restrict__ w2_2,
                                 float* __restrict__ w1_3, float* __restrict__ w2_3,
                                 float* __restrict__ w1_4, float* __restrict__ w2_4) {
    int idx = blockIdx.x * blockDim.x + threadIdx.x;   // [0, 2*23040)
    if (idx >= 2 * 23040) return;
    int which = idx >= 23040;
    int r = which ? idx - 23040 : idx;
    float* base;
    int stride, Wl;
    if (r < 12288)      { base = which ? w2_1 : w1_1; stride = 272; Wl = 256; }
    else if (r < 18432) { base = which ? w2_2 : w1_2; stride = 144; Wl = 128; r -= 12288; }
    else if (r < 21504) { base = which ? w2_3 : w1_3; stride = 80;  Wl = 64;  r -= 18432; }
    else                { base = which ? w2_4 : w1_4; stride = 48;  Wl = 32;  r -= 21504; }
    float* row = base + (size_t)r * stride;
    f4u z = {0.f, 0.f, 0.f, 0.f};
    *(f4u*)(row - 8) = z;
    *(f4u*)(row - 4) = z;
    *(f4u*)(row + Wl) = z;
    *(f4u*)(row + Wl + 4) = z;
}

// acc layout: CS sums at acc[l*48 + img]; SSIM sums at acc[256 + l*48 + img]
__global__ void finalize_kernel(const float* __restrict__ acc, float* __restrict__ out) {
    __shared__ float vals[16];
    int t = threadIdx.x;
    if (t < 16) {
        const float w[5] = {0.0448f, 0.2856f, 0.3001f, 0.2363f, 0.1333f};
        float v = 1.f;
#pragma unroll
        for (int l = 0; l < 5; ++l) {
            int Hl = 512 >> l;
            float denom = 3.f * (float)Hl * (float)Hl;
            const float* src = (l < 4) ? (acc + l * 48) : (acc + 256 + l * 48);
            float m = src[3 * t] + src[3 * t + 1] + src[3 * t + 2];
            m = m / denom;
            m = fmaxf(m, 0.f);
            v *= powf(m, w[l]);
        }
        vals[t] = v;
    }
    __syncthreads();
    if (t == 0) {
        float s = 0.f;
        for (int i = 0; i < 16; ++i) s += vals[i];
        out[0] = s / 16.f;
    }
}

extern "C" void kernel_launch(void* const* d_in, const int* in_sizes, int n_in,
                              void* d_out, int out_size, void* d_ws, size_t ws_size,
                              hipStream_t stream) {
    const float* img1 = (const float*)d_in[0];
    const float* img2 = (const float*)d_in[1];
    float* out = (float*)d_out;
    float* ws = (float*)d_ws;

    float* acc = ws;
    size_t off = 512;

    // padded level-1..4 arrays: stride Wl+16, pointer offset +8
    float* a1[5];
    float* a2[5];
    int strideL[5];
    strideL[0] = 512;
    for (int l = 1; l < 5; ++l) {
        int Hl = 512 >> l;
        strideL[l] = Hl + 16;
        a1[l] = ws + off + 8; off += (size_t)48 * Hl * strideL[l];
    }
    for (int l = 1; l < 5; ++l) {
        int Hl = 512 >> l;
        a2[l] = ws + off + 8; off += (size_t)48 * Hl * strideL[l];
    }

    // Path A needs padded L0 copies too: 2 x 48*512*528 floats
    size_t offA = off;
    float* p0a = ws + offA + 8; offA += (size_t)48 * 512 * 528;
    float* p0b = ws + offA + 8; offA += (size_t)48 * 512 * 528;
    const bool bigWS = (ws_size >= offA * sizeof(float));

    hipMemsetAsync(acc, 0, 512 * sizeof(float), stream);
    halo_zero_kernel<<<(2 * 23040 + 255) / 256, 256, 0, stream>>>(
        a1[1], a2[1], a1[2], a2[2], a1[3], a2[3], a1[4], a2[4]);

    if (bigWS) {
        // ---- pad L0 -> interior-only everywhere (no edge dispatch) ----
        a1[0] = p0a; a2[0] = p0b; strideL[0] = 528;
        size_t chunks = (size_t)2 * 48 * 512 * 132;
        pad_l0_kernel<<<(int)((chunks + 255) / 256), 256, 0, stream>>>(
            img1, img2, p0a - 8, p0b - 8);

        // L0: 8 strips, chunkRows 32 -> 6144 waves, 1536 blocks
        msssim_slide<false><<<1536, NT, 0, stream>>>(
            a1[0], a2[0], 528, a1[1], a2[1], strideL[1],
            acc, acc + 256, 512, 512, 0, 1, 8, 16, 32);
        // L1: 4 strips, crows 16 -> 768 blocks
        msssim_slide<false><<<768, NT, 0, stream>>>(
            a1[1], a2[1], strideL[1], a1[2], a2[2], strideL[2],
            acc + 48, acc + 256 + 48, 256, 256, 0, 1, 4, 16, 16);
        // L2: 2 strips, crows 8 -> 384 blocks
        msssim_slide<false><<<384, NT, 0, stream>>>(
            a1[2], a2[2], strideL[2], a1[3], a2[3], strideL[3],
            acc + 96, acc + 256 + 96, 128, 128, 0, 1, 2, 16, 8);
        // L3: 1 strip, crows 8 -> 96 blocks
        msssim_slide<false><<<96, NT, 0, stream>>>(
            a1[3], a2[3], strideL[3], a1[4], a2[4], strideL[4],
            acc + 144, acc + 256 + 144, 64, 64, 0, 1, 1, 8, 8);
        // L4: 1 strip, crows 8 -> 48 blocks
        msssim_slide<false><<<48, NT, 0, stream>>>(
            a1[4], a2[4], strideL[4], nullptr, nullptr, 0,
            acc + 192, acc + 256 + 192, 32, 32, 0, 1, 1, 4, 8);
    } else {
        // ---- fallback: exact round-14 launcher (interior + edge split) ----
        a1[0] = (float*)img1; a2[0] = (float*)img2;
        int chunksY = 512 / 32;
        msssim_slide<false><<<48 * 6 * chunksY / 4, NT, 0, stream>>>(
            a1[0], a2[0], 512, a1[1], a2[1], strideL[1],
            acc, acc + 256, 512, 512, 1, 1, 6, chunksY, 32);
        msssim_slide<true><<<48 * 2 * chunksY / 4, NT, 0, stream>>>(
            a1[0], a2[0], 512, a1[1], a2[1], strideL[1],
            acc, acc + 256, 512, 512, 0, 7, 2, chunksY, 32);
        for (int l = 1; l < 5; ++l) {
            int Hl = 512 >> l;
            int strips = (Hl + 63) / 64;
            int chunkRows = (l == 1) ? 16 : 8;
            int cy = Hl / chunkRows;
            int waves = 48 * strips * cy;
            float* pp1 = (l < 4) ? a1[l + 1] : nullptr;
            float* pp2 = (l < 4) ? a2[l + 1] : nullptr;
            int so = (l < 4) ? strideL[l + 1] : 0;
            msssim_slide<false><<<waves / 4, NT, 0, stream>>>(
                a1[l], a2[l], strideL[l], pp1, pp2, so,
                acc + l * 48, acc + 256 + l * 48,
                Hl, Hl, 0, 1, strips, cy, chunkRows);
        }
    }
    finalize_kernel<<<1, 64, 0, stream>>>(acc, out);
}

// Round 21
// 196.800 us; speedup vs baseline: 1.3021x; 1.0987x over previous
//
#include <hip/hip_runtime.h>

#define NT 256   // 4 independent waves per block; no barriers anywhere

typedef float v2f __attribute__((ext_vector_type(2)));
typedef float f4u __attribute__((ext_vector_type(4), aligned(4)));
typedef float f4a __attribute__((ext_vector_type(4), aligned(16)));

// Gaussian(sigma=1.5, 11 taps), normalized; 0 outside [0,10]
__device__ __forceinline__ constexpr float Wj(int j) {
    return (j < 0 || j > 10) ? 0.f :
           (j == 0 || j == 10) ? 0.00102838f :
           (j == 1 || j == 9)  ? 0.00759878f :
           (j == 2 || j == 8)  ? 0.03600077f :
           (j == 3 || j == 7)  ? 0.10936069f :
           (j == 4 || j == 6)  ? 0.21300553f : 0.26601172f;
}

// Sliding-window MS-SSIM level kernel, depth-2 pipeline, slim body
// (r14/r20-verified math). ALL waves use the vector load path; L0 edge
// strips read from narrow pre-padded 80-col bands (ex1/ex2), selected by
// a uniform per-wave branch at setup time.
__global__ __attribute__((amdgpu_flat_work_group_size(NT, NT), amdgpu_waves_per_eu(2, 4)))
void msssim_slide(
    const float* __restrict__ x1, const float* __restrict__ x2, int strideIn,
    const float* __restrict__ ex1, const float* __restrict__ ex2,
    float* __restrict__ p1, float* __restrict__ p2, int strideOut,
    float* __restrict__ accCS, float* __restrict__ accSSIM,
    int H, int W, int nStrips, int chunksY, int chunkRows)
{
    const int t = threadIdx.x;
    const int lane = t & 63;

    // ---- bijective XCD swizzle (gridDim.x always a multiple of 8) ----
    const int cpx = gridDim.x >> 3;
    const int lb = (blockIdx.x & 7) * cpx + (blockIdx.x >> 3);
    const int wid = lb * (NT / 64) + (t >> 6);

    const int perImg = nStrips * chunksY;
    const int img = wid / perImg;
    const int rem = wid - img * perImg;
    const int strip = rem / chunksY;           // vertical-first within image
    const int chunk = rem - strip * chunksY;
    const int cc = strip * 64 + lane;          // my output column
    const int r0 = chunk * chunkRows;          // first output row (EVEN)
    const int hEnd = r0 + chunkRows + 5;       // last input row + 1
    const bool laneValid = (cc < W);
    const bool doPool = (p1 != nullptr);

    // ---- per-wave base-pointer/stride selection (uniform, setup-only) ----
    const float* __restrict__ base1;
    const float* __restrict__ base2;
    int sIn;
    if (ex1 != nullptr && (strip == 0 || strip == nStrips - 1)) {
        const int side = (strip != 0);
        const size_t eoff = ((size_t)(side * 48 + img)) * H * 80;
        const int adj = side ? -(W - 72) : 8;   // col c -> band index
        base1 = ex1 + eoff + adj;
        base2 = ex2 + eoff + adj;
        sIn = 80;
    } else {
        base1 = x1 + (size_t)img * H * strideIn;
        base2 = x2 + (size_t)img * H * strideIn;
        sIn = strideIn;
    }

    const size_t imgOut = doPool ? (size_t)img * (H >> 1) * strideOut : 0;
    float* __restrict__ q1 = doPool ? (p1 + imgOut) : nullptr;
    float* __restrict__ q2 = doPool ? (p2 + imgOut) : nullptr;

    float nA1[12], nA2[12], nB1[12], nB2[12];  // ping-pong row windows
    v2f psd[11], psq[11];       // pending V-outputs ring (assign-first lifecycle)
    float prs1 = 0.f, prs2 = 0.f;  // pool row-pair partial sums
    float cs_s = 0.f, ssim_s = 0.f;

    auto loadRow = [&](int h, float (&d1)[12], float (&d2)[12]) {
        if (h < 0 || h >= H || !laneValid) return;   // zero-pad rows / idle lanes
        const float* __restrict__ r1 = base1 + (size_t)h * sIn + (cc - 5);
        const float* __restrict__ r2 = base2 + (size_t)h * sIn + (cc - 5);
        const f4u* a4 = reinterpret_cast<const f4u*>(r1);
        const f4u* b4 = reinterpret_cast<const f4u*>(r2);
        f4u A0 = a4[0], A1 = a4[1], A2 = a4[2];
        f4u B0 = b4[0], B1 = b4[1], B2 = b4[2];
#pragma unroll
        for (int j = 0; j < 4; ++j) { d1[j] = A0[j]; d1[4 + j] = A1[j]; d1[8 + j] = A2[j]; }
#pragma unroll
        for (int j = 0; j < 4; ++j) { d2[j] = B0[j]; d2[4 + j] = B1[j]; d2[8 + j] = B2[j]; }
    };

    // prologue: rows r0-5 (buffer A) and r0-4 (buffer B) in flight
    loadRow(r0 - 5, nA1, nA2);
    loadRow(r0 - 4, nB1, nB2);

    const float C1 = 0.0001f, C2 = 0.0009f;

    // hb = r0-5 is ODD (r0 even) => pp even <-> h odd, pp odd <-> h even
    for (int hb = r0 - 5; hb < hEnd; hb += 22) {
#pragma unroll
        for (int pp = 0; pp < 22; ++pp) {
            const int h = hb + pp;
            if (h < hEnd) {
                const int p = pp % 11;                       // ring phase
                float (&x1w)[12] = (pp & 1) ? nB1 : nA1;     // compile-time parity
                float (&x2w)[12] = (pp & 1) ? nB2 : nA2;

                // ---- 1. consume buffered row h: H-filter 4 moments ----
                v2f acc_sd = (v2f){0.f, 0.f}, acc_sq = (v2f){0.f, 0.f};
                if (h >= 0 && h < H) {
                    if (doPool && h >= r0 && h < r0 + chunkRows) {
                        if ((pp & 1) == 1) {                 // h EVEN: save pair
                            prs1 = x1w[5] + x1w[6];
                            prs2 = x2w[5] + x2w[6];
                        } else if (!(lane & 1) && laneValid) {  // h ODD: write pooled
                            size_t po = (size_t)(h >> 1) * strideOut + (cc >> 1);
                            q1[po] = 0.25f * (prs1 + x1w[5] + x1w[6]);
                            q2[po] = 0.25f * (prs2 + x2w[5] + x2w[6]);
                        }
                    }
#pragma unroll
                    for (int j = 0; j < 11; ++j) {
                        // {s, d} = {x1+x2, x1-x2} in ONE packed fma
                        v2f xx1 = {x1w[j], x1w[j]};
                        v2f xx2 = {x2w[j], x2w[j]};
                        v2f sd = __builtin_elementwise_fma((v2f){1.f, -1.f}, xx2, xx1);
                        v2f w2 = {Wj(j), Wj(j)};
                        acc_sd = __builtin_elementwise_fma(w2, sd, acc_sd);
                        acc_sq = __builtin_elementwise_fma(w2, sd * sd, acc_sq);
                    }
                }
                // ---- 2. issue row h+2 into the just-consumed buffer ----
                if (h + 2 < hEnd) loadRow(h + 2, x1w, x2w);
                // ---- 3. V-ring update: row h feeds outputs h-5 .. h+5 ----
#pragma unroll
                for (int k = 0; k < 11; ++k) {
                    const int slot = (p + 5 - k + 11) % 11;
                    v2f w2 = {Wj(k), Wj(k)};
                    if (k == 0) {
                        psd[slot] = w2 * acc_sd;
                        psq[slot] = w2 * acc_sq;
                    } else {
                        psd[slot] = __builtin_elementwise_fma(w2, acc_sd, psd[slot]);
                        psq[slot] = __builtin_elementwise_fma(w2, acc_sq, psq[slot]);
                    }
                }
                // ---- 4. emit completed output row o = h-5 (rcp-based) ----
                if (h - 5 >= r0) {
                    const int es = (p + 6) % 11;
                    v2f m2 = psd[es] * psd[es];      // {Sm^2, Dm^2}
                    v2f t1 = psq[es] - m2;           // {SS-Sm^2, DD-Dm^2}
                    float num_cs = 0.5f * (t1.x - t1.y) + C2;
                    float den_cs = 0.5f * (t1.x + t1.y) + C2;
                    float num_ss = 0.5f * (m2.x - m2.y) + C1;
                    float den_ss = 0.5f * (m2.x + m2.y) + C1;
                    float cs = num_cs * __builtin_amdgcn_rcpf(den_cs);
                    float ss = num_ss * cs * __builtin_amdgcn_rcpf(den_ss);
                    if (laneValid) { cs_s += cs; ssim_s += ss; }
                }
            }
        }
    }

    // ---- wave reduction -> 2 atomics per wave ----
#pragma unroll
    for (int off = 32; off > 0; off >>= 1) {
        cs_s += __shfl_down(cs_s, off);
        ssim_s += __shfl_down(ssim_s, off);
    }
    if (lane == 0) {
        atomicAdd(&accCS[img], cs_s);
        atomicAdd(&accSSIM[img], ssim_s);
    }
}

// Build the two 80-col L0 edge bands per image, both inputs:
// e[side][img][row][80]; side 0 = cols -8..71 (left, -8..-1 zero),
// side 1 = cols 440..519 (right, 512..519 zero). One thread per f4.
__global__ void pad_edges_kernel(const float* __restrict__ s1, const float* __restrict__ s2,
                                 float* __restrict__ e1, float* __restrict__ e2) {
    const int PER = 2 * 48 * 512 * 20;               // f4 chunks per input
    int idx = blockIdx.x * blockDim.x + threadIdx.x; // [0, 2*PER)
    int which = idx >= PER;
    int r = which ? idx - PER : idx;
    int c4 = r % 20; r /= 20;
    int row = r % 512; r /= 512;
    int img = r % 48;
    int side = r / 48;
    const float* __restrict__ src = which ? s2 : s1;
    float* __restrict__ dst = (which ? e2 : e1) +
        (((size_t)(side * 48 + img) * 512 + row) * 80) + c4 * 4;
    int colBase = (side ? 440 : -8) + c4 * 4;
    f4a v = {0.f, 0.f, 0.f, 0.f};
    if (side == 0 ? (c4 >= 2) : (c4 < 18))
        v = *(const f4a*)(src + ((size_t)img * 512 + row) * 512 + colBase);
    *(f4a*)dst = v;
}

// Zero the 8-col left/right halos of the padded level-1..4 arrays
__global__ void halo_zero_kernel(float* __restrict__ w1_1, float* __restrict__ w2_1,
                                 float* __restrict__ w1_2, float* __restrict__ w2_2,
                                 float* __restrict__ w1_3, float* __restrict__ w2_3,
                                 float* __restrict__ w1_4, float* __restrict__ w2_4) {
    int idx = blockIdx.x * blockDim.x + threadIdx.x;   // [0, 2*23040)
    if (idx >= 2 * 23040) return;
    int which = idx >= 23040;
    int r = which ? idx - 23040 : idx;
    float* base;
    int stride, Wl;
    if (r < 12288)      { base = which ? w2_1 : w1_1; stride = 272; Wl = 256; }
    else if (r < 18432) { base = which ? w2_2 : w1_2; stride = 144; Wl = 128; r -= 12288; }
    else if (r < 21504) { base = which ? w2_3 : w1_3; stride = 80;  Wl = 64;  r -= 18432; }
    else                { base = which ? w2_4 : w1_4; stride = 48;  Wl = 32;  r -= 21504; }
    float* row = base + (size_t)r * stride;
    f4u z = {0.f, 0.f, 0.f, 0.f};
    *(f4u*)(row - 8) = z;
    *(f4u*)(row - 4) = z;
    *(f4u*)(row + Wl) = z;
    *(f4u*)(row + Wl + 4) = z;
}

// acc layout: CS sums at acc[l*48 + img]; SSIM sums at acc[256 + l*48 + img]
__global__ void finalize_kernel(const float* __restrict__ acc, float* __restrict__ out) {
    __shared__ float vals[16];
    int t = threadIdx.x;
    if (t < 16) {
        const float w[5] = {0.0448f, 0.2856f, 0.3001f, 0.2363f, 0.1333f};
        float v = 1.f;
#pragma unroll
        for (int l = 0; l < 5; ++l) {
            int Hl = 512 >> l;
            float denom = 3.f * (float)Hl * (float)Hl;
            const float* src = (l < 4) ? (acc + l * 48) : (acc + 256 + l * 48);
            float m = src[3 * t] + src[3 * t + 1] + src[3 * t + 2];
            m = m / denom;
            m = fmaxf(m, 0.f);
            v *= powf(m, w[l]);
        }
        vals[t] = v;
    }
    __syncthreads();
    if (t == 0) {
        float s = 0.f;
        for (int i = 0; i < 16; ++i) s += vals[i];
        out[0] = s / 16.f;
    }
}

extern "C" void kernel_launch(void* const* d_in, const int* in_sizes, int n_in,
                              void* d_out, int out_size, void* d_ws, size_t ws_size,
                              hipStream_t stream) {
    const float* img1 = (const float*)d_in[0];
    const float* img2 = (const float*)d_in[1];
    float* out = (float*)d_out;
    float* ws = (float*)d_ws;

    float* acc = ws;
    size_t off = 512;

    // padded level-1..4 arrays: stride Wl+16, pointer offset +8
    float* a1[5];
    float* a2[5];
    int strideL[5];
    strideL[0] = 512;
    for (int l = 1; l < 5; ++l) {
        int Hl = 512 >> l;
        strideL[l] = Hl + 16;
        a1[l] = ws + off + 8; off += (size_t)48 * Hl * strideL[l];
    }
    for (int l = 1; l < 5; ++l) {
        int Hl = 512 >> l;
        a2[l] = ws + off + 8; off += (size_t)48 * Hl * strideL[l];
    }

    // L0 edge bands: 2 inputs x [2 sides][48][512][80] floats
    float* e1 = ws + off; off += (size_t)2 * 48 * 512 * 80;
    float* e2 = ws + off; off += (size_t)2 * 48 * 512 * 80;

    hipMemsetAsync(acc, 0, 512 * sizeof(float), stream);
    halo_zero_kernel<<<(2 * 23040 + 255) / 256, 256, 0, stream>>>(
        a1[1], a2[1], a1[2], a2[2], a1[3], a2[3], a1[4], a2[4]);
    pad_edges_kernel<<<(2 * 2 * 48 * 512 * 20) / 256, 256, 0, stream>>>(
        img1, img2, e1, e2);

    // L0: 8 strips (edges via bands), chunkRows 32 -> 6144 waves, 1536 blocks
    msssim_slide<<<1536, NT, 0, stream>>>(
        img1, img2, 512, e1, e2, a1[1], a2[1], strideL[1],
        acc, acc + 256, 512, 512, 8, 16, 32);
    // L1: 4 strips, crows 16 -> 768 blocks
    msssim_slide<<<768, NT, 0, stream>>>(
        a1[1], a2[1], strideL[1], nullptr, nullptr, a1[2], a2[2], strideL[2],
        acc + 48, acc + 256 + 48, 256, 256, 4, 16, 16);
    // L2: 2 strips, crows 8 -> 384 blocks
    msssim_slide<<<384, NT, 0, stream>>>(
        a1[2], a2[2], strideL[2], nullptr, nullptr, a1[3], a2[3], strideL[3],
        acc + 96, acc + 256 + 96, 128, 128, 2, 16, 8);
    // L3: 1 strip, crows 8 -> 96 blocks
    msssim_slide<<<96, NT, 0, stream>>>(
        a1[3], a2[3], strideL[3], nullptr, nullptr, a1[4], a2[4], strideL[4],
        acc + 144, acc + 256 + 144, 64, 64, 1, 8, 8);
    // L4: 1 strip, crows 8 -> 48 blocks
    msssim_slide<<<48, NT, 0, stream>>>(
        a1[4], a2[4], strideL[4], nullptr, nullptr, nullptr, nullptr, 0,
        acc + 192, acc + 256 + 192, 32, 32, 1, 4, 8);

    finalize_kernel<<<1, 64, 0, stream>>>(acc, out);
}